// Round 17
// baseline (68.191 us; speedup 1.0000x reference)
//
#include <hip/hip_runtime.h>

#define TLEN   500000
#define NITER  100
#define DHALF  6                  // band half-width
#define NOFF   (2*DHALF+1)        // 13 offsets
#define STRIP  20                 // edge strip width
#define EWIN   32                 // edge window
#define WROW   128                // padded weights per source-row k (layout 1)
#define W2OFF  (12*WROW)          // layout 2: [i][h][80] at ws+W2OFF (1280 floats)
#define NCONV  ((TLEN - 2*STRIP + 63) / 64)   // 7812 blocks x 64 cols

// ============ K1: band weights (blocks 0-11) + edge strips (blocks 12,13) ============
// (R12 kernel, measured-good & validated; adds a second, per-(i,half)-contiguous
// weight export used by the conv kernel.)
__global__ __launch_bounds__(256) void band_and_edges(
    const float* __restrict__ xs, const float* __restrict__ ys,
    const float* __restrict__ F, const float* __restrict__ H,
    const float* __restrict__ Q, const float* __restrict__ R,
    const float* __restrict__ gam,
    float* __restrict__ wout,            // layout 1: [k][d*8+i], pad 0
    float* __restrict__ wout2,           // layout 2: [i][h][80], first 78 = w[r][d]
    float* __restrict__ out)
{
  __shared__ double dQaug[8][16];
  __shared__ double dRaug[4][8];
  __shared__ double dFtQi[64], dHtRi[32], dA1[64], dB2[64];
  __shared__ float fmats[224];
  __shared__ __align__(16) float st[2][34][8];   // ping-pong column states

  const int tid = threadIdx.x;
  const int b   = blockIdx.x;
  const int r8  = (tid >> 3) & 7;
  const int c8  = tid & 7;

  if (tid < 64) {
    dQaug[r8][c8]     = (double)Q[r8*8 + c8];
    dQaug[r8][c8 + 8] = (c8 == r8) ? 1.0 : 0.0;
  } else if (tid < 96) {
    int t = tid - 64, rr = t >> 3, cr = t & 7;
    dRaug[rr][cr] = (cr < 4) ? (double)R[rr*4 + cr] : ((cr - 4 == rr) ? 1.0 : 0.0);
  }
  __syncthreads();
  for (int col = 0; col < 8; ++col) {      // Gauss-Jordan (Q,R SPD: no pivoting)
    double piv = 1, fq = 0, p1 = 0, p2 = 0, m1 = 0, m2 = 0;
    double rpiv = 1, frr = 0, pr = 0, mr = 0;
    const bool doQ = tid < 64;
    const bool doR = (tid >= 64 && tid < 96 && col < 4);
    if (doQ) {
      piv = dQaug[col][col]; fq = dQaug[r8][col];
      p1 = dQaug[col][c8];   p2 = dQaug[col][c8 + 8];
      m1 = dQaug[r8][c8];    m2 = dQaug[r8][c8 + 8];
    }
    if (doR) {
      int t = tid - 64, rr = t >> 3, cr = t & 7;
      rpiv = dRaug[col][col]; frr = dRaug[rr][col];
      pr = dRaug[col][cr];    mr = dRaug[rr][cr];
    }
    __syncthreads();
    if (doQ) {
      dQaug[r8][c8]     = (r8 == col) ? m1 / piv : m1 - fq * (p1 / piv);
      dQaug[r8][c8 + 8] = (r8 == col) ? m2 / piv : m2 - fq * (p2 / piv);
    }
    if (doR) {
      int t = tid - 64, rr = t >> 3, cr = t & 7;
      dRaug[rr][cr] = (rr == col) ? mr / rpiv : mr - frr * (pr / rpiv);
    }
    __syncthreads();
  }
  if (tid < 64) {
    double s = 0.0;
    #pragma unroll
    for (int k = 0; k < 8; ++k) s += (double)F[k*8 + r8] * dQaug[k][c8 + 8];
    dFtQi[r8*8 + c8] = s;
    dA1[r8*8 + c8] = (c8 == 0) ? 0.0 : -dQaug[r8][c8 + 8];
  } else if (tid < 96) {
    int t = tid - 64, i = t >> 2, j = t & 3;
    double s = 0.0;
    #pragma unroll
    for (int k = 0; k < 4; ++k) s += (double)H[k*8 + i] * dRaug[k][j + 4];
    dHtRi[i*4 + j] = s;
  }
  __syncthreads();
  if (tid < 64) dB2[r8*8 + c8] = (c8 == 7) ? 0.0 : dFtQi[r8*8 + c8];
  __syncthreads();
  {
    const double g = (double)gam[0];
    if (tid < 64) {
      double sp = 0.0;
      #pragma unroll
      for (int k = 0; k < 8; ++k) sp -= dA1[r8*8 + k] * (double)F[k*8 + c8];
      double t2 = dA1[r8*8 + c8];
      #pragma unroll
      for (int k = 0; k < 8; ++k) t2 -= dB2[r8*8 + k] * (double)F[k*8 + c8];
      #pragma unroll
      for (int k = 0; k < 4; ++k) t2 -= dHtRi[r8*4 + k] * (double)H[k*8 + c8];
      fmats[       c8*8 + r8] = (float)(((r8 == c8) ? 1.0 : 0.0) + g * t2);
      fmats[ 64 +  c8*8 + r8] = (float)(g * sp);
      fmats[128 +  c8*8 + r8] = (float)(g * dB2[r8*8 + c8]);
    } else if (tid < 96) {
      int t = tid - 64, i = t >> 2, j = t & 3;
      fmats[192 + j*8 + i] = (float)(g * dHtRi[i*4 + j]);
    }
  }
  __syncthreads();

  const int i = tid & 7;
  const int g = tid >> 3;
  float cmr[8], pmr[8], fur[7];
  #pragma unroll
  for (int k = 0; k < 8; ++k) {
    cmr[k] = fmats[       k*8 + i];
    pmr[k] = fmats[ 64 +  k*8 + i];
    if (k < 7) fur[k] = fmats[128 + k*8 + i];
  }
  float* const stf = (float*)st;
  const int BUF = 34*8;

  if (b < 12) {
    const int c = b;
    const bool act = tid < NOFF*8;
    const int s = g + 1;
    for (int idx = tid; idx < 2*BUF; idx += 256) stf[idx] = 0.0f;
    __syncthreads();
    if (act && c < 8 && s == DHALF + 1 && i == c) st[0][s][i] = 1.0f;
    const float seed = (act && c >= 8 && s == DHALF + 1) ? fmats[192 + (c - 8)*8 + i] : 0.0f;
    __syncthreads();
    int p = 0;
    float last = 0.0f;
    #pragma unroll 1
    for (int it = 0; it < NITER; ++it) {
      if (act) {
        const float* sp_ = stf + p*BUF;
        const float4 o0 = *(const float4*)(sp_ + s*8);
        const float4 o1 = *(const float4*)(sp_ + s*8 + 4);
        const float4 u0 = *(const float4*)(sp_ + (s + 1)*8);
        const float4 u1 = *(const float4*)(sp_ + (s + 1)*8 + 4);
        const float4 d0 = *(const float4*)(sp_ + (s - 1)*8);
        const float4 d1 = *(const float4*)(sp_ + (s - 1)*8 + 4);
        float a0 = seed, a1 = 0.0f, a2 = 0.0f;
        a0 = fmaf(cmr[0], o0.x, a0); a0 = fmaf(cmr[1], o0.y, a0);
        a0 = fmaf(cmr[2], o0.z, a0); a0 = fmaf(cmr[3], o0.w, a0);
        a0 = fmaf(cmr[4], o1.x, a0); a0 = fmaf(cmr[5], o1.y, a0);
        a0 = fmaf(cmr[6], o1.z, a0); a0 = fmaf(cmr[7], o1.w, a0);
        a1 = fmaf(pmr[0], u0.x, a1); a1 = fmaf(pmr[1], u0.y, a1);
        a1 = fmaf(pmr[2], u0.z, a1); a1 = fmaf(pmr[3], u0.w, a1);
        a1 = fmaf(pmr[4], u1.x, a1); a1 = fmaf(pmr[5], u1.y, a1);
        a1 = fmaf(pmr[6], u1.z, a1); a1 = fmaf(pmr[7], u1.w, a1);
        a2 = fmaf(fur[0], d0.x, a2); a2 = fmaf(fur[1], d0.y, a2);
        a2 = fmaf(fur[2], d0.z, a2); a2 = fmaf(fur[3], d0.w, a2);
        a2 = fmaf(fur[4], d1.x, a2); a2 = fmaf(fur[5], d1.y, a2);
        a2 = fmaf(fur[6], d1.z, a2);
        last = a0 + a1 + a2;
        stf[(p^1)*BUF + s*8 + i] = last;
      }
      __syncthreads();
      p ^= 1;
    }
    if (act) {
      wout[c*WROW + (s - 1)*8 + i] = last;
      const int h2 = (c >= 6) ? 1 : 0;            // conv half owning this k
      const int kk = c - h2*6;                    // row within half
      wout2[i*160 + h2*80 + kk*13 + (s - 1)] = last;
    }
    if (tid >= NOFF*8 && tid < WROW) wout[c*WROW + tid] = 0.0f;
    return;
  }

  const bool left = (b == 12);
  const int col  = g;
  const int gcol = left ? col : (TLEN - EWIN + col);
  const int sL = (col > 0) ? col - 1 : 0;
  const int sR = (col < EWIN - 1) ? col + 1 : EWIN - 1;
  const float xv = xs[i*TLEN + gcol];
  float gyv;
  {
    gyv = fmats[192 +      i] * ys[0*TLEN + gcol];
    gyv = fmaf(fmats[192 +  8 + i], ys[1*TLEN + gcol], gyv);
    gyv = fmaf(fmats[192 + 16 + i], ys[2*TLEN + gcol], gyv);
    gyv = fmaf(fmats[192 + 24 + i], ys[3*TLEN + gcol], gyv);
  }
  st[0][col][i] = xv;
  __syncthreads();
  int p = 0;
  float last = xv;
  #pragma unroll 1
  for (int it = 0; it < NITER; ++it) {
    const float* sp_ = stf + p*BUF;
    const float4 o0 = *(const float4*)(sp_ + col*8);
    const float4 o1 = *(const float4*)(sp_ + col*8 + 4);
    const float4 l0 = *(const float4*)(sp_ + sL*8);
    const float4 l1 = *(const float4*)(sp_ + sL*8 + 4);
    const float4 q0 = *(const float4*)(sp_ + sR*8);
    const float4 q1 = *(const float4*)(sp_ + sR*8 + 4);
    float a0 = gyv, a1 = 0.0f, a2 = 0.0f;
    a0 = fmaf(cmr[0], o0.x, a0); a0 = fmaf(cmr[1], o0.y, a0);
    a0 = fmaf(cmr[2], o0.z, a0); a0 = fmaf(cmr[3], o0.w, a0);
    a0 = fmaf(cmr[4], o1.x, a0); a0 = fmaf(cmr[5], o1.y, a0);
    a0 = fmaf(cmr[6], o1.z, a0); a0 = fmaf(cmr[7], o1.w, a0);
    a1 = fmaf(pmr[0], l0.x, a1); a1 = fmaf(pmr[1], l0.y, a1);
    a1 = fmaf(pmr[2], l0.z, a1); a1 = fmaf(pmr[3], l0.w, a1);
    a1 = fmaf(pmr[4], l1.x, a1); a1 = fmaf(pmr[5], l1.y, a1);
    a1 = fmaf(pmr[6], l1.z, a1); a1 = fmaf(pmr[7], l1.w, a1);
    a2 = fmaf(fur[0], q0.x, a2); a2 = fmaf(fur[1], q0.y, a2);
    a2 = fmaf(fur[2], q0.z, a2); a2 = fmaf(fur[3], q0.w, a2);
    a2 = fmaf(fur[4], q1.x, a2); a2 = fmaf(fur[5], q1.y, a2);
    a2 = fmaf(fur[6], q1.z, a2);
    last = a0 + a1 + a2;
    stf[(p^1)*BUF + col*8 + i] = last;
    __syncthreads();
    p ^= 1;
  }
  if (left ? (col < STRIP) : (col >= EWIN - STRIP)) out[i*TLEN + gcol] = last;
}

// ============ K2: conv — register-resident weights, k-split across 2 waves ============
// Thread (h = wave, i = out row, g = col group) owns 8 cols x row i x 6 k-rows.
// 78 weights loaded ONCE into VGPRs (20 contiguous float4). Hot loop: 6x
// {6 float4 z-loads + 104 FMA} — no weight/LDS/SMEM traffic. Halves combine
// through 2 KB LDS with one barrier; wave 0 stores.
__global__ __launch_bounds__(128) void kgm_conv(
    const float* __restrict__ xs, const float* __restrict__ ys,
    const float* __restrict__ w2, float* __restrict__ out)
{
  __shared__ float part[64 * 8];
  const int tid = threadIdx.x;
  const int h   = tid >> 6;            // wave: 0 -> k 0..5, 1 -> k 6..11
  const int i   = (tid >> 3) & 7;      // output row
  const int g   = tid & 7;             // column group
  int c0 = STRIP + blockIdx.x * 64 + g * 8;
  const bool str = (c0 < TLEN - STRIP);          // groups all-or-nothing (mult of 8)
  if (c0 > TLEN - STRIP - 8) c0 = TLEN - STRIP - 8;

  // one-time weight load: 80 floats (first 78 used), 16B-aligned contiguous
  float wf[80];
  {
    const float* wb = w2 + i*160 + h*80;
    #pragma unroll
    for (int t = 0; t < 20; ++t) {
      float4 v = *(const float4*)(wb + 4*t);
      wf[4*t] = v.x; wf[4*t+1] = v.y; wf[4*t+2] = v.z; wf[4*t+3] = v.w;
    }
  }

  float acc[8] = {0,0,0,0,0,0,0,0};
  #pragma unroll
  for (int r = 0; r < 6; ++r) {
    const int k = h*6 + r;
    const float* src = ((k < 8) ? (xs + k*TLEN) : (ys + (k-8)*TLEN)) + c0;
    float z[24];                        // cols [c0-8, c0+16), all 16B-aligned
    #pragma unroll
    for (int t = 0; t < 6; ++t) {
      float4 v = *(const float4*)(src - 8 + 4*t);
      z[4*t] = v.x; z[4*t+1] = v.y; z[4*t+2] = v.z; z[4*t+3] = v.w;
    }
    #pragma unroll
    for (int d = 0; d < NOFF; ++d) {
      const float w = wf[r*13 + d];
      #pragma unroll
      for (int j = 0; j < 8; ++j)       // out col c0+j <- in col c0+j+d-6
        acc[j] = fmaf(w, z[d + 2 + j], acc[j]);
    }
  }

  if (h == 1) {
    #pragma unroll
    for (int j = 0; j < 8; ++j) part[(i*8 + g)*8 + j] = acc[j];
  }
  __syncthreads();
  if (h == 0 && str) {
    const float* pp = part + (i*8 + g)*8;
    float4 o0, o1;
    o0.x = acc[0] + pp[0]; o0.y = acc[1] + pp[1];
    o0.z = acc[2] + pp[2]; o0.w = acc[3] + pp[3];
    o1.x = acc[4] + pp[4]; o1.y = acc[5] + pp[5];
    o1.z = acc[6] + pp[6]; o1.w = acc[7] + pp[7];
    *(float4*)(out + i*TLEN + c0)     = o0;
    *(float4*)(out + i*TLEN + c0 + 4) = o1;
  }
}

extern "C" void kernel_launch(void* const* d_in, const int* in_sizes, int n_in,
                              void* d_out, int out_size, void* d_ws, size_t ws_size,
                              hipStream_t stream)
{
  (void)in_sizes; (void)n_in; (void)out_size; (void)ws_size;
  const float* xs = (const float*)d_in[0];
  const float* ys = (const float*)d_in[1];
  const float* F  = (const float*)d_in[2];
  const float* H  = (const float*)d_in[3];
  const float* Q  = (const float*)d_in[4];
  const float* R  = (const float*)d_in[5];
  const float* ga = (const float*)d_in[6];
  float* ws  = (float*)d_ws;     // [0,1536): [k][d*8+i]; [1536,2816): [i][h][80]
  float* out = (float*)d_out;
  band_and_edges<<<14, 256, 0, stream>>>(xs, ys, F, H, Q, R, ga, ws, ws + W2OFF, out);
  kgm_conv<<<NCONV, 128, 0, stream>>>(xs, ys, ws + W2OFF, out);
}